// Round 1
// baseline (829.743 us; speedup 1.0000x reference)
//
#include <hip/hip_runtime.h>
#include <math.h>

#define IMG_H 1024
#define IMG_W 1024
#define KS 5
#define PAD 2

__global__ __launch_bounds__(256)
void erosion5x5_kernel(const float* __restrict__ img,
                       const float* __restrict__ filt,
                       float* __restrict__ out)
{
    const int tid = threadIdx.x;
    const int y   = blockIdx.x;          // row
    const int bc  = blockIdx.y;          // fused batch*channel plane
    const int x0  = tid * 4;             // first of 4 output columns

    // Preload 5x5 filter into registers (uniform address -> scalar loads, L2-hot)
    float F[25];
#pragma unroll
    for (int i = 0; i < 25; ++i) F[i] = filt[i];

    const size_t plane = (size_t)bc * (IMG_H * IMG_W);
    const float* base = img + plane;

    float acc0 = INFINITY, acc1 = INFINITY, acc2 = INFINITY, acc3 = INFINITY;

#pragma unroll
    for (int i = 0; i < KS; ++i) {
        const int r = y + i - PAD;
        if (r < 0 || r >= IMG_H) continue;   // block-uniform branch
        const float* row = base + (size_t)r * IMG_W;

        // need columns x0-2 .. x0+5 (8 values)
        float c0, c1, c2, c3, c4, c5, c6, c7;
        if (x0 >= 4 && x0 + 8 <= IMG_W) {
            // fast path: 3 aligned float4 loads covering x0-4 .. x0+7
            float4 a = *(const float4*)(row + x0 - 4);
            float4 b = *(const float4*)(row + x0);
            float4 d = *(const float4*)(row + x0 + 4);
            c0 = a.z; c1 = a.w;
            c2 = b.x; c3 = b.y; c4 = b.z; c5 = b.w;
            c6 = d.x; c7 = d.y;
        } else {
            // edge threads (x0==0 or x0==1020): element-wise with +inf fill
            float ctmp[8];
#pragma unroll
            for (int t = 0; t < 8; ++t) {
                int x = x0 - 2 + t;
                ctmp[t] = (x >= 0 && x < IMG_W) ? row[x] : INFINITY;
            }
            c0 = ctmp[0]; c1 = ctmp[1]; c2 = ctmp[2]; c3 = ctmp[3];
            c4 = ctmp[4]; c5 = ctmp[5]; c6 = ctmp[6]; c7 = ctmp[7];
        }

        const float* Fr = &F[i * KS];
        // j = 0
        acc0 = fminf(acc0, c0 - Fr[0]);
        acc1 = fminf(acc1, c1 - Fr[0]);
        acc2 = fminf(acc2, c2 - Fr[0]);
        acc3 = fminf(acc3, c3 - Fr[0]);
        // j = 1
        acc0 = fminf(acc0, c1 - Fr[1]);
        acc1 = fminf(acc1, c2 - Fr[1]);
        acc2 = fminf(acc2, c3 - Fr[1]);
        acc3 = fminf(acc3, c4 - Fr[1]);
        // j = 2
        acc0 = fminf(acc0, c2 - Fr[2]);
        acc1 = fminf(acc1, c3 - Fr[2]);
        acc2 = fminf(acc2, c4 - Fr[2]);
        acc3 = fminf(acc3, c5 - Fr[2]);
        // j = 3
        acc0 = fminf(acc0, c3 - Fr[3]);
        acc1 = fminf(acc1, c4 - Fr[3]);
        acc2 = fminf(acc2, c5 - Fr[3]);
        acc3 = fminf(acc3, c6 - Fr[3]);
        // j = 4
        acc0 = fminf(acc0, c4 - Fr[4]);
        acc1 = fminf(acc1, c5 - Fr[4]);
        acc2 = fminf(acc2, c6 - Fr[4]);
        ac3:
        acc3 = fminf(acc3, c7 - Fr[4]);
    }

    float4 o;
    o.x = acc0; o.y = acc1; o.z = acc2; o.w = acc3;
    *(float4*)(out + plane + (size_t)y * IMG_W + x0) = o;
}

extern "C" void kernel_launch(void* const* d_in, const int* in_sizes, int n_in,
                              void* d_out, int out_size, void* d_ws, size_t ws_size,
                              hipStream_t stream) {
    const float* img  = (const float*)d_in[0];
    const float* filt = (const float*)d_in[1];
    float* out = (float*)d_out;

    const int n_planes = in_sizes[0] / (IMG_H * IMG_W);  // 32*3 = 96

    dim3 grid(IMG_H, n_planes);
    dim3 block(256);
    erosion5x5_kernel<<<grid, block, 0, stream>>>(img, filt, out);
}